// Round 3
// baseline (175.388 us; speedup 1.0000x reference)
//
#include <hip/hip_runtime.h>
#include <hip/hip_bf16.h>

// Problem constants (SpanPairPairedLayer): B=8, S=1024, D=1024, P=4096, DR=512, DO=512
// GEMM1: [8192 x 1024] @ [1024 x 512] -> C1 (bf16, ws)
// GEMM2: gathered [32768 x 1024] @ [1024 x 512] -> out (fp32)

#define BM 128
#define BN 128
#define BK 32

typedef __attribute__((ext_vector_type(8))) short s8v;    // 8 bf16 (4 VGPRs)
typedef __attribute__((ext_vector_type(4))) float f4v;    // MFMA accumulator

__device__ __forceinline__ unsigned short f2bf(float f) {
    unsigned int u = __float_as_uint(f);
    u += 0x7fffu + ((u >> 16) & 1u);   // round-to-nearest-even
    return (unsigned short)(u >> 16);
}

__device__ __forceinline__ void gload16(const void* g, void* l) {
    __builtin_amdgcn_global_load_lds(
        (const __attribute__((address_space(1))) void*)g,
        (__attribute__((address_space(3))) void*)l, 16, 0, 0);
}

// ---- prep: span fp32 -> bf16, 8 elems/thread ----
__global__ void conv_span_k(const float* __restrict__ in, unsigned short* __restrict__ out) {
    size_t i = (size_t)blockIdx.x * blockDim.x + threadIdx.x;  // 8 floats per thread
    const f4v* p = (const f4v*)in + i * 2;
    f4v v0 = p[0], v1 = p[1];
    s8v o;
#pragma unroll
    for (int j = 0; j < 4; ++j) {
        o[j]     = (short)f2bf(v0[j]);
        o[4 + j] = (short)f2bf(v1[j]);
    }
    *(s8v*)(out + i * 8) = o;
}

// ---- prep: W [1024][512] fp32 -> WT [512][1024] bf16 ----
__global__ void transpose_w_k(const float* __restrict__ in, unsigned short* __restrict__ out) {
    __shared__ float tile[32][33];
    int k0 = blockIdx.x * 32, n0 = blockIdx.y * 32;
    int tx = threadIdx.x, ty = threadIdx.y;
    tile[ty][tx] = in[(size_t)(k0 + ty) * 512 + n0 + tx];
    __syncthreads();
    out[(size_t)(n0 + ty) * 1024 + k0 + tx] = f2bf(tile[tx][ty]);
}

// ---- GEMM: MODE 1 = span1 (A direct, bf16 out), MODE 2 = pair GEMM (gathered A, fp32 out)
template <int MODE>
__global__ __launch_bounds__(256)
void gemm_tile(const unsigned short* __restrict__ Abase,   // MODE1: spanB [8192][1024]; MODE2: C1 [8192][512]
               const unsigned short* __restrict__ BT,      // [512][1024] bf16 (N-major)
               const float* __restrict__ bias,             // [512]
               const int* __restrict__ pairs,              // [B][P][2] int32 (MODE2)
               void* __restrict__ outp) {
    __shared__ unsigned short Asm[BM * BK];
    __shared__ unsigned short Bsm[BN * BK];

    const int t = threadIdx.x;
    const int lane = t & 63;
    const int w = t >> 6;          // wave 0..3
    const int wr = w >> 1;         // 2x2 wave grid, each wave 64x64
    const int wc = w & 1;
    const int bm0 = blockIdx.x * BM;
    const int bn0 = blockIdx.y * BN;

    // staging assignment: thread t stages rows (t>>2) and 64+(t>>2), 8 elems at k-offset (t&3)*8
    const int sr = t >> 2;
    const int sk = (t & 3) * 8;

    const unsigned short *aP0, *aP1, *aC0, *aC1;
    if constexpr (MODE == 1) {
        aP0 = Abase + (size_t)(bm0 + sr) * 1024 + sk;
        aP1 = Abase + (size_t)(bm0 + 64 + sr) * 1024 + sk;
        aC0 = aP0; aC1 = aP1;
    } else {
        int g0 = bm0 + sr, g1 = g0 + 64;
        int b0 = g0 >> 12, b1 = g1 >> 12;   // 4096 pair-rows per batch
        // pairs flat int32: (b*4096 + p)*2 + j == g*2 + j
        int ip0 = pairs[(size_t)g0 * 2 + 0];
        int ic0 = pairs[(size_t)g0 * 2 + 1];
        int ip1 = pairs[(size_t)g1 * 2 + 0];
        int ic1 = pairs[(size_t)g1 * 2 + 1];
        aP0 = Abase + (size_t)(b0 * 1024 + ip0) * 512 + sk;   // parent half (k<512)
        aC0 = Abase + (size_t)(b0 * 1024 + ic0) * 512 + sk;   // child half (k>=512)
        aP1 = Abase + (size_t)(b1 * 1024 + ip1) * 512 + sk;
        aC1 = Abase + (size_t)(b1 * 1024 + ic1) * 512 + sk;
    }
    const unsigned short* bP0 = BT + (size_t)(bn0 + sr) * 1024 + sk;
    const unsigned short* bP1 = BT + (size_t)(bn0 + 64 + sr) * 1024 + sk;

    // wave-uniform LDS bases for global_load_lds (lane l lands at base + l*16)
    char* aLds0 = (char*)Asm + w * 1024;
    char* aLds1 = (char*)Asm + 4096 + w * 1024;
    char* bLds0 = (char*)Bsm + w * 1024;
    char* bLds1 = (char*)Bsm + 4096 + w * 1024;

    f4v acc[4][4] = {};

    const int kk = (lane >> 4) * 8;   // k-offset of this lane's fragment
    const int fr = lane & 15;         // row (A) / col (B) within fragment

    for (int k0 = 0; k0 < 1024; k0 += BK) {
        const unsigned short *s0, *s1;
        int ka;
        if constexpr (MODE == 2) {
            if (k0 < 512) { s0 = aP0; s1 = aP1; ka = k0; }
            else          { s0 = aC0; s1 = aC1; ka = k0 - 512; }
        } else {
            s0 = aP0; s1 = aP1; ka = k0;
        }

        __syncthreads();                 // previous iter's ds_reads complete
        gload16(s0 + ka, aLds0);
        gload16(s1 + ka, aLds1);
        gload16(bP0 + k0, bLds0);
        gload16(bP1 + k0, bLds1);
        __syncthreads();                 // compiler drains vmcnt before barrier

        s8v af[4], bb[4];
#pragma unroll
        for (int m = 0; m < 4; ++m)
            af[m] = *(const s8v*)&Asm[(wr * 64 + m * 16 + fr) * BK + kk];
#pragma unroll
        for (int n = 0; n < 4; ++n)
            bb[n] = *(const s8v*)&Bsm[(wc * 64 + n * 16 + fr) * BK + kk];
#pragma unroll
        for (int m = 0; m < 4; ++m)
#pragma unroll
            for (int n = 0; n < 4; ++n)
                acc[m][n] = __builtin_amdgcn_mfma_f32_16x16x32_bf16(af[m], bb[n], acc[m][n], 0, 0, 0);
    }

    // epilogue: C/D layout col=lane&15, row=(lane>>4)*4+reg
    const int orow0 = bm0 + wr * 64 + (lane >> 4) * 4;
    const int ocol0 = bn0 + wc * 64 + fr;
#pragma unroll
    for (int m = 0; m < 4; ++m) {
#pragma unroll
        for (int n = 0; n < 4; ++n) {
            int col = ocol0 + n * 16;
            float bv = bias[col];
#pragma unroll
            for (int r = 0; r < 4; ++r) {
                int row = orow0 + m * 16 + r;
                float v = fmaxf(acc[m][n][r] + bv, 0.0f);
                if constexpr (MODE == 1)
                    ((unsigned short*)outp)[(size_t)row * 512 + col] = f2bf(v);
                else
                    ((float*)outp)[(size_t)row * 512 + col] = v;
            }
        }
    }
}

extern "C" void kernel_launch(void* const* d_in, const int* in_sizes, int n_in,
                              void* d_out, int out_size, void* d_ws, size_t ws_size,
                              hipStream_t stream) {
    const float* span  = (const float*)d_in[0];
    const int*   pairs = (const int*)d_in[1];    // int64 in reference, int32 in harness (JAX x64 off)
    const float* W1    = (const float*)d_in[2];
    const float* b1    = (const float*)d_in[3];
    const float* Wr    = (const float*)d_in[4];
    const float* br    = (const float*)d_in[5];
    float*       out   = (float*)d_out;

    // workspace layout (bytes): spanB 16MB | W1T 1MB | WrT 1MB | C1 8MB  (~26MB total)
    char* ws = (char*)d_ws;
    unsigned short* spanB = (unsigned short*)ws;
    unsigned short* W1T   = (unsigned short*)(ws + 16777216);
    unsigned short* WrT   = (unsigned short*)(ws + 16777216 + 1048576);
    unsigned short* C1    = (unsigned short*)(ws + 16777216 + 2097152);

    conv_span_k<<<4096, 256, 0, stream>>>(span, spanB);                       // 8.4M elems
    transpose_w_k<<<dim3(32, 16), dim3(32, 32), 0, stream>>>(W1, W1T);
    transpose_w_k<<<dim3(32, 16), dim3(32, 32), 0, stream>>>(Wr, WrT);

    gemm_tile<1><<<dim3(64, 4),  256, 0, stream>>>(spanB, W1T, b1, nullptr, C1);
    gemm_tile<2><<<dim3(256, 4), 256, 0, stream>>>(C1,    WrT, br, pairs,   out);
}